// Round 1
// baseline (98.155 us; speedup 1.0000x reference)
//
#include <hip/hip_runtime.h>

#define BLK 256
#define QPT 8        // query points per thread
#define SLICES 16    // target slices per direction
#define TT 512       // targets per slice tile (= 8192 / SLICES)

__global__ __launch_bounds__(256) void init_mins(unsigned int* mins, int n) {
    int i = blockIdx.x * 256 + threadIdx.x;
    if (i < n) mins[i] = 0x7f800000u;  // +inf bit pattern
}

// dir 0: queries = pred (pc_p), targets = gt  -> minP region
// dir 1: queries = gt  (pc_gt), targets = pred -> minG region
__global__ __launch_bounds__(BLK) void chamfer_min(
    const float* __restrict__ gt, const float* __restrict__ pp,
    unsigned int* __restrict__ minP, unsigned int* __restrict__ minG,
    int M, int N)
{
    const int dir = (blockIdx.z >= SLICES) ? 1 : 0;
    const int s   = blockIdx.z - dir * SLICES;
    const float* __restrict__ Q = dir ? gt : pp;
    const float* __restrict__ T = dir ? pp : gt;
    unsigned int* mins = dir ? minG : minP;
    const int NQ = dir ? N : M;
    const int NT = dir ? M : N;
    const int b  = blockIdx.y;

    // stage target slice into LDS as (-2x, -2y, -2z, |t|^2)
    __shared__ float4 sT[TT];
    {
        const float* tb = T + ((size_t)b * NT + (size_t)s * TT) * 3;
        for (int j = threadIdx.x; j < TT; j += BLK) {
            float x = tb[3 * j], y = tb[3 * j + 1], z = tb[3 * j + 2];
            sT[j] = make_float4(-2.f * x, -2.f * y, -2.f * z,
                                x * x + y * y + z * z);
        }
    }
    __syncthreads();

    const int q0 = blockIdx.x * (BLK * QPT) + threadIdx.x * QPT;
    if (q0 >= NQ) return;

    // load 8 query points (24 floats = 6 aligned float4 loads)
    const float* qb = Q + ((size_t)b * NQ + q0) * 3;
    float4 f0 = *(const float4*)(qb + 0);
    float4 f1 = *(const float4*)(qb + 4);
    float4 f2 = *(const float4*)(qb + 8);
    float4 f3 = *(const float4*)(qb + 12);
    float4 f4 = *(const float4*)(qb + 16);
    float4 f5 = *(const float4*)(qb + 20);

    float qx[QPT], qy[QPT], qz[QPT], a[QPT], best[QPT];
    qx[0] = f0.x; qy[0] = f0.y; qz[0] = f0.z;
    qx[1] = f0.w; qy[1] = f1.x; qz[1] = f1.y;
    qx[2] = f1.z; qy[2] = f1.w; qz[2] = f2.x;
    qx[3] = f2.y; qy[3] = f2.z; qz[3] = f2.w;
    qx[4] = f3.x; qy[4] = f3.y; qz[4] = f3.z;
    qx[5] = f3.w; qy[5] = f4.x; qz[5] = f4.y;
    qx[6] = f4.z; qy[6] = f4.w; qz[6] = f5.x;
    qx[7] = f5.y; qy[7] = f5.z; qz[7] = f5.w;
#pragma unroll
    for (int q = 0; q < QPT; ++q) {
        a[q] = qx[q] * qx[q] + qy[q] * qy[q] + qz[q] * qz[q];
        best[q] = 3.0e38f;
    }

    // min over targets of (|t|^2 - 2 q.t); add |q|^2 back at the end.
#pragma unroll 4
    for (int j = 0; j < TT; ++j) {
        float4 t = sT[j];
#pragma unroll
        for (int q = 0; q < QPT; ++q) {
            float acc = __builtin_fmaf(qz[q], t.z, t.w);
            acc = __builtin_fmaf(qy[q], t.y, acc);
            acc = __builtin_fmaf(qx[q], t.x, acc);
            best[q] = fminf(best[q], acc);
        }
    }

    unsigned int* mp = mins + (size_t)b * NQ + q0;
#pragma unroll
    for (int q = 0; q < QPT; ++q) {
        float d = fmaxf(best[q] + a[q], 0.f);  // clamp tiny negative cancellation
        atomicMin(&mp[q], __float_as_uint(d));
    }
}

__device__ double block_reduce_d(double v) {
    __shared__ double red[4];
    for (int o = 32; o > 0; o >>= 1) v += __shfl_down(v, o);
    int lane = threadIdx.x & 63, w = threadIdx.x >> 6;
    if (lane == 0) red[w] = v;
    __syncthreads();
    if (threadIdx.x == 0) v = red[0] + red[1] + red[2] + red[3];
    return v;
}

__global__ __launch_bounds__(256) void reduce1(const unsigned int* __restrict__ mins,
                                               double* __restrict__ partials,
                                               int EM, int E, double wP, double wG) {
    double acc = 0.0;
    for (int i = blockIdx.x * 256 + threadIdx.x; i < E; i += 256 * 256)
        acc += (double)__uint_as_float(mins[i]) * (i < EM ? wP : wG);
    double s = block_reduce_d(acc);
    if (threadIdx.x == 0) partials[blockIdx.x] = s;
}

__global__ __launch_bounds__(256) void reduce2(const double* __restrict__ partials,
                                               float* __restrict__ out) {
    double s = block_reduce_d(partials[threadIdx.x]);
    if (threadIdx.x == 0) out[0] = (float)s;
}

extern "C" void kernel_launch(void* const* d_in, const int* in_sizes, int n_in,
                              void* d_out, int out_size, void* d_ws, size_t ws_size,
                              hipStream_t stream) {
    const float* gt = (const float*)d_in[0];  // pc_gt (B,N,3)
    const float* pp = (const float*)d_in[1];  // pc_p  (B,M,3)
    const int B = 8;
    const int N = in_sizes[0] / (B * 3);
    const int M = in_sizes[1] / (B * 3);
    const int EM = B * M, EN = B * N, E = EM + EN;

    unsigned int* mins = (unsigned int*)d_ws;            // E uints (minP | minG)
    double* partials = (double*)((char*)d_ws + (size_t)E * 4);  // 256 doubles
    float* out = (float*)d_out;

    init_mins<<<(E + 255) / 256, 256, 0, stream>>>(mins, E);

    const int NQmax = (M > N) ? M : N;
    dim3 grid((NQmax + BLK * QPT - 1) / (BLK * QPT), B, 2 * SLICES);
    chamfer_min<<<grid, BLK, 0, stream>>>(gt, pp, mins, mins + EM, M, N);

    reduce1<<<256, 256, 0, stream>>>(mins, partials, EM, E,
                                     1.0 / (double)EM, 1.0 / (double)EN);
    reduce2<<<1, 256, 0, stream>>>(partials, out);
}